// Round 5
// baseline (554.791 us; speedup 1.0000x reference)
//
#include <hip/hip_runtime.h>
#include <hip/hip_bf16.h>
#include <stdint.h>

#define B_ 64
#define T_ 128
#define L_ 32
#define D_ 128
#define K_ 64

// workspace offsets in 4-byte units
#define FLAG_OFF 0                                 // 128 per-block detect flags
#define SM_OFF   256
#define ENC_OFF  (SM_OFF + B_*T_)                 // [B][T][D] f32
#define SW_OFF   (ENC_OFF + B_*T_*D_)             // [B][T][D] f32  (s @ Ww)
#define KS_OFF   (SW_OFF + B_*T_*D_)              // [B][T][K] f32  (keys . s)
#define KV_OFF   (KS_OFF + B_*T_*K_)              // [B][K][D] f32  (keys @ Vw)

typedef __attribute__((ext_vector_type(8))) short short8b;   // 8 bf16 = 4 VGPR
typedef __attribute__((ext_vector_type(4))) float f32x4;

__device__ __forceinline__ float sigmoidf_(float x){ return 1.0f/(1.0f + __expf(-x)); }

__device__ __forceinline__ unsigned short bfb(float x){
  __hip_bfloat16 h = __float2bfloat16(x);                    // RNE
  return __builtin_bit_cast(unsigned short, h);
}
__device__ __forceinline__ float bf2f(unsigned short u){
  return __uint_as_float(((unsigned)u) << 16);
}

// --- K0: parallel detect of prgrph_mask dtype (1-byte bool vs 4-byte int32).
__global__ __launch_bounds__(256) void k_detect(const uint8_t* __restrict__ m,
                                                int* __restrict__ flags){
  const unsigned* w = (const unsigned*)m;
  const int base = blockIdx.x * 512;
  unsigned acc = 0;
  acc |= w[base + threadIdx.x]       & 0xFFFFFF00u;
  acc |= w[base + threadIdx.x + 256] & 0xFFFFFF00u;
  int any = __syncthreads_or((int)(acc != 0u));
  if(threadIdx.x == 0) flags[blockIdx.x] = any;   // 1 => bool bytes, 0 => int32
}

// --- K1: per (b,t): enc row, SW = enc@Ww, KS = keys.enc, sent_mask ---
__global__ __launch_bounds__(128) void k_enc(const int* __restrict__ prg,
                                             const uint8_t* __restrict__ pm8,
                                             const float* __restrict__ emb,
                                             const float* __restrict__ pos,
                                             const float* __restrict__ Ww,
                                             const float* __restrict__ keys,
                                             float* __restrict__ W){
  const int bt = blockIdx.x;
  const int b  = bt / T_;
  const int d  = threadIdx.x;
  int myf  = ((const int*)W)[FLAG_OFF + (d & 127)];
  int flag = __syncthreads_or(myf);
  __shared__ float keysl[K_*129];
  __shared__ float encl[D_];
  for(int r=0;r<K_;r++) keysl[r*129 + d] = keys[(b*K_ + r)*D_ + d];
  const int* pmi = (const int*)pm8;
  float acc = 0.f; int anym = 0;
  for(int l=0;l<L_;l++){
    int off = bt*L_ + l;
    int m = flag ? (int)pm8[off] : pmi[off];
    if(m){
      anym = 1;
      int idx = prg[off];
      acc += emb[idx*D_ + d] * pos[l*D_ + d];
    }
  }
  encl[d] = acc;
  W[ENC_OFF + bt*D_ + d] = acc;
  __syncthreads();
  float sw = 0.f;
  for(int e=0;e<D_;e++) sw += encl[e] * Ww[e*D_ + d];
  W[SW_OFF + bt*D_ + d] = sw;
  if(d < K_){
    float ks = 0.f;
    for(int dd=0;dd<D_;dd++) ks += keysl[d*129 + dd] * encl[dd];
    W[KS_OFF + bt*K_ + d] = ks;
  }
  if(d==0) W[SM_OFF + bt] = anym ? 1.f : 0.f;
}

// --- K2: KV = keys @ Vw ---
__global__ __launch_bounds__(128) void k_kv(const float* __restrict__ keys,
                                            const float* __restrict__ Vw,
                                            float* __restrict__ W){
  const int bk = blockIdx.x;
  const int d  = threadIdx.x;
  __shared__ float kr[D_];
  kr[d] = keys[bk*D_ + d];
  __syncthreads();
  float acc = 0.f;
  for(int e=0;e<D_;e++) acc += kr[e] * Vw[e*D_ + d];
  W[KV_OFF + bk*D_ + d] = acc;
}

// --- K3: MFMA scan, barrier-free (single-wave block), deferred normalization.
// State vY = unnormalized v; h = n*v with n = rsqrt(sum v^2) computed in-step,
// off the critical path (MFMA is linear: U^T h = n * (U^T v)).
// C-layout: e = lane&15, d = 16rt+4q+r  (q = lane>>4, r = acc reg).
__global__ __launch_bounds__(64,1) void k_scan(const float* __restrict__ W,
                                               const float* __restrict__ Uw,
                                               float* __restrict__ out){
  const int b    = blockIdx.x >> 2;
  const int kg   = blockIdx.x & 3;
  const int lane = threadIdx.x;
  const int e    = lane & 15;
  const int q    = lane >> 4;
  const int swz  = (e << 2) & 0x3C;     // XOR swizzle on u32-index bits 2..5

  __shared__ unsigned hrep[2048];       // [0..1023]=hi pairs, [1024..2047]=lo pairs

  // ---- one-time: U^T A-fragments.  A[row=e][k=8q+j] of tile(rt,kc) = Uw[32kc+8q+j][16rt+e]
  short8b ufrag[8][4];
  #pragma unroll
  for(int rt=0; rt<8; ++rt){
    #pragma unroll
    for(int kc=0; kc<4; ++kc){
      const float* src = &Uw[(32*kc + 8*q)*D_ + 16*rt + e];
      short8b f;
      #pragma unroll
      for(int j=0;j<8;++j) f[j] = (short)bfb(src[j*D_]);
      ufrag[rt][kc] = f;
    }
  }
  // kv in Y layout (folded into sw at prefetch time)
  f32x4 kvv[8];
  {
    const float* kvp = &W[KV_OFF + (b*K_ + kg*16 + e)*D_ + 4*q];
    #pragma unroll
    for(int rt=0;rt<8;++rt) kvv[rt] = *(const f32x4*)&kvp[16*rt];
  }
  f32x4 vY[8];
  #pragma unroll
  for(int rt=0;rt<8;++rt) vY[rt] = 0.f;

  const float* ENC = &W[ENC_OFF + b*T_*D_];
  const float* SWg = &W[SW_OFF  + b*T_*D_];
  const float* KSg = &W[KS_OFF  + b*T_*K_];
  const float* SM  = &W[SM_OFF  + b*T_];

  // prefetch: sv = enc row; sk = sw row + kv (folded)
  auto loadstep = [&](int t, f32x4 (&sv)[8], f32x4 (&sk)[8], float& ks, float& sm){
    const float* sp = &ENC[t*D_ + 4*q];
    const float* wp = &SWg[t*D_ + 4*q];
    #pragma unroll
    for(int rt=0;rt<8;++rt){
      sv[rt] = *(const f32x4*)&sp[16*rt];
      f32x4 w = *(const f32x4*)&wp[16*rt];
      #pragma unroll
      for(int r=0;r<4;++r) sk[rt][r] = w[r] + kvv[rt][r];
    }
    ks = KSg[t*K_ + kg*16 + e];
    sm = SM[t];
  };

  auto dostep = [&](const f32x4 (&sv)[8], const f32x4 (&skv)[8], float ks, float sm){
    if(sm != 0.f){
      // --- repack v (Y layout) -> B-frag layout, hi + lo residual, via LDS.
      // Single-wave block: no __syncthreads needed (in-order LDS pipe + compiler waits).
      #pragma unroll
      for(int rt=0;rt<8;++rt){
        float x0=vY[rt][0], x1=vY[rt][1], x2=vY[rt][2], x3=vY[rt][3];
        unsigned short h0=bfb(x0), h1=bfb(x1), h2=bfb(x2), h3=bfb(x3);
        unsigned hi0 = ((unsigned)h1<<16) | h0;
        unsigned hi1 = ((unsigned)h3<<16) | h2;
        unsigned short l0=bfb(x0-bf2f(h0)), l1=bfb(x1-bf2f(h1));
        unsigned short l2=bfb(x2-bf2f(h2)), l3=bfb(x3-bf2f(h3));
        unsigned lo0 = ((unsigned)l1<<16) | l0;
        unsigned lo1 = ((unsigned)l3<<16) | l2;
        int a = e*64 + ((8*rt + 2*q) ^ swz);
        uint2 wh; wh.x=hi0; wh.y=hi1;
        uint2 wl; wl.x=lo0; wl.y=lo1;
        *(uint2*)&hrep[a]        = wh;
        *(uint2*)&hrep[1024 + a] = wl;
      }
      // --- norm + gate partials (parallel to the LDS round trip / MFMA)
      float ns = 0.f, gs = 0.f;
      #pragma unroll
      for(int rt=0;rt<8;++rt){
        #pragma unroll
        for(int r=0;r<4;++r){
          ns += vY[rt][r]*vY[rt][r];
          gs += vY[rt][r]*sv[rt][r];
        }
      }
      ns += __shfl_xor(ns,16);
      ns += __shfl_xor(ns,32);
      gs += __shfl_xor(gs,16);
      gs += __shfl_xor(gs,32);
      float n = rsqrtf(fmaxf(ns, 1e-12f));
      float g = sigmoidf_(fmaf(n, gs, ks));

      // --- read B-frags
      short8b bhi[4], blo[4];
      #pragma unroll
      for(int kc=0;kc<4;++kc){
        int a = e*64 + ((16*kc + 4*q) ^ swz);
        bhi[kc] = *(const short8b*)&hrep[a];
        blo[kc] = *(const short8b*)&hrep[1024 + a];
      }

      // --- acc = U^T v_q  (scale by n afterwards)
      f32x4 acc[8];
      #pragma unroll
      for(int rt=0;rt<8;++rt) acc[rt] = 0.f;
      #pragma unroll
      for(int rt=0;rt<8;++rt){
        #pragma unroll
        for(int kc=0;kc<4;++kc){
          acc[rt] = __builtin_amdgcn_mfma_f32_16x16x32_bf16(ufrag[rt][kc], bhi[kc], acc[rt], 0,0,0);
          acc[rt] = __builtin_amdgcn_mfma_f32_16x16x32_bf16(ufrag[rt][kc], blo[kc], acc[rt], 0,0,0);
        }
      }

      // --- epilogue: x = n*acc + (kv+sw); ht = sigmoid(x); v' = n*v + g*ht
      #pragma unroll
      for(int rt=0;rt<8;++rt){
        #pragma unroll
        for(int r=0;r<4;++r){
          float x  = fmaf(n, acc[rt][r], skv[rt][r]);
          float ht = sigmoidf_(x);
          vY[rt][r] = fmaf(g, ht, n*vY[rt][r]);
        }
      }
    }
  };

  // software pipeline: named A/B buffers, unrolled by 2 (no runtime-indexed regs)
  f32x4 svA[8], skA[8], svB[8], skB[8];
  float ksA, smA, ksB, smB;
  loadstep(0, svA, skA, ksA, smA);
  #pragma unroll 1
  for(int t=0; t<T_; t+=2){
    loadstep(t+1, svB, skB, ksB, smB);      // prefetch t+1 while computing t
    dostep(svA, skA, ksA, smA);
    int t2 = (t+2 < T_) ? (t+2) : 0;        // tail: harmless dummy reload
    loadstep(t2, svA, skA, ksA, smA);
    dostep(svB, skB, ksB, smB);
  }

  // final normalize h = n*v and write out[b, kg*16+e, 16rt+4q+r]
  float ns = 0.f;
  #pragma unroll
  for(int rt=0;rt<8;++rt){
    #pragma unroll
    for(int r=0;r<4;++r) ns += vY[rt][r]*vY[rt][r];
  }
  ns += __shfl_xor(ns,16);
  ns += __shfl_xor(ns,32);
  float n = rsqrtf(fmaxf(ns, 1e-12f));
  float* op = &out[(b*K_ + kg*16 + e)*D_ + 4*q];
  #pragma unroll
  for(int rt=0;rt<8;++rt){
    f32x4 o;
    #pragma unroll
    for(int r=0;r<4;++r) o[r] = vY[rt][r]*n;
    *(f32x4*)&op[16*rt] = o;
  }
}

extern "C" void kernel_launch(void* const* d_in, const int* in_sizes, int n_in,
                              void* d_out, int out_size, void* d_ws, size_t ws_size,
                              hipStream_t stream) {
  const int*     prg  = (const int*)d_in[0];
  const uint8_t* pm   = (const uint8_t*)d_in[1];
  const float*   emb  = (const float*)d_in[2];
  const float*   pos  = (const float*)d_in[3];
  const float*   Uw   = (const float*)d_in[4];
  const float*   Vw   = (const float*)d_in[5];
  const float*   Ww   = (const float*)d_in[6];
  const float*   keys = (const float*)d_in[7];
  float* W   = (float*)d_ws;
  float* out = (float*)d_out;

  hipLaunchKernelGGL(k_detect, dim3(128),    dim3(256), 0, stream, pm, (int*)d_ws + FLAG_OFF);
  hipLaunchKernelGGL(k_enc,    dim3(B_*T_),  dim3(128), 0, stream, prg, pm, emb, pos, Ww, keys, W);
  hipLaunchKernelGGL(k_kv,     dim3(B_*K_),  dim3(128), 0, stream, keys, Vw, W);
  hipLaunchKernelGGL(k_scan,   dim3(B_*4),   dim3(64),  0, stream, W, Uw, out);
}

// Round 6
// 515.621 us; speedup vs baseline: 1.0760x; 1.0760x over previous
//
#include <hip/hip_runtime.h>
#include <hip/hip_bf16.h>
#include <stdint.h>

#define B_ 64
#define T_ 128
#define L_ 32
#define D_ 128
#define K_ 64

// workspace offsets in 4-byte units
#define FLAG_OFF 0                                 // 128 per-block detect flags
#define SM_OFF   256
#define ENC_OFF  (SM_OFF + B_*T_)                 // [B][T][D] f32
#define SW_OFF   (ENC_OFF + B_*T_*D_)             // [B][T][D] f32  (s @ Ww)
#define KS_OFF   (SW_OFF + B_*T_*D_)              // [B][T][K] f32  (keys . s)
#define KV_OFF   (KS_OFF + B_*T_*K_)              // [B][K][D] f32  (keys @ Vw)

typedef __attribute__((ext_vector_type(8))) short short8b;   // 8 bf16 = 4 VGPR
typedef __attribute__((ext_vector_type(4))) float f32x4;

union frag_cast { uint4 u; short8b s; };

__device__ __forceinline__ float sigmoidf_(float x){ return 1.0f/(1.0f + __expf(-x)); }

__device__ __forceinline__ unsigned short bfb(float x){
  __hip_bfloat16 h = __float2bfloat16(x);                    // RNE
  return __builtin_bit_cast(unsigned short, h);
}
__device__ __forceinline__ float bf2f(unsigned short u){
  return __uint_as_float(((unsigned)u) << 16);
}

// --- K0: parallel detect of prgrph_mask dtype (1-byte bool vs 4-byte int32).
__global__ __launch_bounds__(256) void k_detect(const uint8_t* __restrict__ m,
                                                int* __restrict__ flags){
  const unsigned* w = (const unsigned*)m;
  const int base = blockIdx.x * 512;
  unsigned acc = 0;
  acc |= w[base + threadIdx.x]       & 0xFFFFFF00u;
  acc |= w[base + threadIdx.x + 256] & 0xFFFFFF00u;
  int any = __syncthreads_or((int)(acc != 0u));
  if(threadIdx.x == 0) flags[blockIdx.x] = any;   // 1 => bool bytes, 0 => int32
}

// --- K1: per (b,t): enc row, SW = enc@Ww, KS = keys.enc, sent_mask ---
__global__ __launch_bounds__(128) void k_enc(const int* __restrict__ prg,
                                             const uint8_t* __restrict__ pm8,
                                             const float* __restrict__ emb,
                                             const float* __restrict__ pos,
                                             const float* __restrict__ Ww,
                                             const float* __restrict__ keys,
                                             float* __restrict__ W){
  const int bt = blockIdx.x;
  const int b  = bt / T_;
  const int d  = threadIdx.x;
  int myf  = ((const int*)W)[FLAG_OFF + (d & 127)];
  int flag = __syncthreads_or(myf);
  __shared__ float keysl[K_*129];
  __shared__ float encl[D_];
  for(int r=0;r<K_;r++) keysl[r*129 + d] = keys[(b*K_ + r)*D_ + d];
  const int* pmi = (const int*)pm8;
  float acc = 0.f; int anym = 0;
  for(int l=0;l<L_;l++){
    int off = bt*L_ + l;
    int m = flag ? (int)pm8[off] : pmi[off];
    if(m){
      anym = 1;
      int idx = prg[off];
      acc += emb[idx*D_ + d] * pos[l*D_ + d];
    }
  }
  encl[d] = acc;
  W[ENC_OFF + bt*D_ + d] = acc;
  __syncthreads();
  float sw = 0.f;
  for(int e=0;e<D_;e++) sw += encl[e] * Ww[e*D_ + d];
  W[SW_OFF + bt*D_ + d] = sw;
  if(d < K_){
    float ks = 0.f;
    for(int dd=0;dd<D_;dd++) ks += keysl[d*129 + dd] * encl[dd];
    W[KS_OFF + bt*K_ + d] = ks;
  }
  if(d==0) W[SM_OFF + bt] = anym ? 1.f : 0.f;
}

// --- K2: KV = keys @ Vw ---
__global__ __launch_bounds__(128) void k_kv(const float* __restrict__ keys,
                                            const float* __restrict__ Vw,
                                            float* __restrict__ W){
  const int bk = blockIdx.x;
  const int d  = threadIdx.x;
  __shared__ float kr[D_];
  kr[d] = keys[bk*D_ + d];
  __syncthreads();
  float acc = 0.f;
  for(int e=0;e<D_;e++) acc += kr[e] * Vw[e*D_ + d];
  W[KV_OFF + bk*D_ + d] = acc;
}

// --- K3: MFMA scan, zero-repack via permuted k-mapping.
// k-index din permutation: din(kc,q,j) = 32kc + 16*(j>>2) + 4q + (j&3).
// With this choice, B-frag(kc) of lane (e,q) = elements vY[2kc+(j>>2)][j&3]
// -> the lane's own C-layout registers. No LDS, no cross-lane repack.
// C-layout: e = lane&15, d = 16rt+4q+r. State vY = unnormalized v (h = n*v).
__global__ __launch_bounds__(64,1) void k_scan(const float* __restrict__ W,
                                               const float* __restrict__ Uw,
                                               float* __restrict__ out){
  const int b    = blockIdx.x >> 2;
  const int kg   = blockIdx.x & 3;
  const int lane = threadIdx.x;
  const int e    = lane & 15;
  const int q    = lane >> 4;

  // ---- one-time: U^T A-frags with the permuted k-mapping.
  // ufrag[rt][kc][j] = bf16( Uw[32kc + 16*(j>>2) + 4q + (j&3)][16rt + e] )
  short8b ufrag[8][4];
  #pragma unroll
  for(int rt=0; rt<8; ++rt){
    #pragma unroll
    for(int kc=0; kc<4; ++kc){
      const float* r0 = &Uw[(32*kc + 4*q)*D_ + 16*rt + e];
      short8b f;
      #pragma unroll
      for(int j=0;j<8;++j) f[j] = (short)bfb(r0[((j>>2)*16 + (j&3))*D_]);
      ufrag[rt][kc] = f;
    }
  }
  // kv in Y layout (folded into sk at prefetch time)
  f32x4 kvv[8];
  {
    const float* kvp = &W[KV_OFF + (b*K_ + kg*16 + e)*D_ + 4*q];
    #pragma unroll
    for(int rt=0;rt<8;++rt) kvv[rt] = *(const f32x4*)&kvp[16*rt];
  }
  f32x4 vY[8];
  #pragma unroll
  for(int rt=0;rt<8;++rt) vY[rt] = 0.f;

  const float* ENC = &W[ENC_OFF + b*T_*D_];
  const float* SWg = &W[SW_OFF  + b*T_*D_];
  const float* KSg = &W[KS_OFF  + b*T_*K_];
  const float* SM  = &W[SM_OFF  + b*T_];

  auto loadstep = [&](int t, f32x4 (&sv)[8], f32x4 (&sk)[8], float& ks, float& sm){
    const float* sp = &ENC[t*D_ + 4*q];
    const float* wp = &SWg[t*D_ + 4*q];
    #pragma unroll
    for(int rt=0;rt<8;++rt){
      sv[rt] = *(const f32x4*)&sp[16*rt];
      f32x4 w = *(const f32x4*)&wp[16*rt];
      #pragma unroll
      for(int r=0;r<4;++r) sk[rt][r] = w[r] + kvv[rt][r];
    }
    ks = KSg[t*K_ + kg*16 + e];
    sm = SM[t];
  };

  // pack one f32x4 into hi-pair + lo-residual-pair u32s
  auto cvt2 = [&](const f32x4& v, uint2& hi, uint2& lo){
    unsigned short h0=bfb(v[0]), h1=bfb(v[1]), h2=bfb(v[2]), h3=bfb(v[3]);
    hi.x = ((unsigned)h1<<16) | h0;
    hi.y = ((unsigned)h3<<16) | h2;
    unsigned short l0=bfb(v[0]-bf2f(h0)), l1=bfb(v[1]-bf2f(h1));
    unsigned short l2=bfb(v[2]-bf2f(h2)), l3=bfb(v[3]-bf2f(h3));
    lo.x = ((unsigned)l1<<16) | l0;
    lo.y = ((unsigned)l3<<16) | l2;
  };

  auto dostep = [&](const f32x4 (&sv)[8], const f32x4 (&skv)[8], float ks, float sm){
    if(sm != 0.f){
      // --- in-lane B-frag pack (hi + lo residual), zero cross-lane movement
      short8b bhi[4], blo[4];
      #pragma unroll
      for(int kc=0;kc<4;++kc){
        uint2 ha, la, hb, lb;
        cvt2(vY[2*kc],   ha, la);
        cvt2(vY[2*kc+1], hb, lb);
        frag_cast fh; fh.u = make_uint4(ha.x, ha.y, hb.x, hb.y);
        frag_cast fl; fl.u = make_uint4(la.x, la.y, lb.x, lb.y);
        bhi[kc] = fh.s;
        blo[kc] = fl.s;
      }
      // --- norm + gate partials (overlap with MFMA issue)
      float ns = 0.f, gs = 0.f;
      #pragma unroll
      for(int rt=0;rt<8;++rt){
        #pragma unroll
        for(int r=0;r<4;++r){
          ns += vY[rt][r]*vY[rt][r];
          gs += vY[rt][r]*sv[rt][r];
        }
      }
      ns += __shfl_xor(ns,16);
      ns += __shfl_xor(ns,32);
      gs += __shfl_xor(gs,16);
      gs += __shfl_xor(gs,32);
      float n = rsqrtf(fmaxf(ns, 1e-12f));
      float g = sigmoidf_(fmaf(n, gs, ks));

      // --- acc = U^T v  (unnormalized; scaled by n in epilogue)
      f32x4 acc[8];
      #pragma unroll
      for(int rt=0;rt<8;++rt) acc[rt] = 0.f;
      #pragma unroll
      for(int rt=0;rt<8;++rt){
        #pragma unroll
        for(int kc=0;kc<4;++kc){
          acc[rt] = __builtin_amdgcn_mfma_f32_16x16x32_bf16(ufrag[rt][kc], bhi[kc], acc[rt], 0,0,0);
          acc[rt] = __builtin_amdgcn_mfma_f32_16x16x32_bf16(ufrag[rt][kc], blo[kc], acc[rt], 0,0,0);
        }
      }

      // --- epilogue: x = n*acc + (kv+sw); ht = sigmoid(x); v' = n*v + g*ht
      #pragma unroll
      for(int rt=0;rt<8;++rt){
        #pragma unroll
        for(int r=0;r<4;++r){
          float x  = fmaf(n, acc[rt][r], skv[rt][r]);
          float ht = sigmoidf_(x);
          vY[rt][r] = fmaf(g, ht, n*vY[rt][r]);
        }
      }
    }
  };

  // software pipeline: named A/B buffers, unrolled by 2 (no runtime-indexed regs)
  f32x4 svA[8], skA[8], svB[8], skB[8];
  float ksA, smA, ksB, smB;
  loadstep(0, svA, skA, ksA, smA);
  #pragma unroll 1
  for(int t=0; t<T_; t+=2){
    loadstep(t+1, svB, skB, ksB, smB);      // prefetch t+1 while computing t
    dostep(svA, skA, ksA, smA);
    int t2 = (t+2 < T_) ? (t+2) : 0;        // tail: harmless dummy reload
    loadstep(t2, svA, skA, ksA, smA);
    dostep(svB, skB, ksB, smB);
  }

  // final normalize h = n*v and write out[b, kg*16+e, 16rt+4q+r]
  float ns = 0.f;
  #pragma unroll
  for(int rt=0;rt<8;++rt){
    #pragma unroll
    for(int r=0;r<4;++r) ns += vY[rt][r]*vY[rt][r];
  }
  ns += __shfl_xor(ns,16);
  ns += __shfl_xor(ns,32);
  float n = rsqrtf(fmaxf(ns, 1e-12f));
  float* op = &out[(b*K_ + kg*16 + e)*D_ + 4*q];
  #pragma unroll
  for(int rt=0;rt<8;++rt){
    f32x4 o;
    #pragma unroll
    for(int r=0;r<4;++r) o[r] = vY[rt][r]*n;
    *(f32x4*)&op[16*rt] = o;
  }
}

extern "C" void kernel_launch(void* const* d_in, const int* in_sizes, int n_in,
                              void* d_out, int out_size, void* d_ws, size_t ws_size,
                              hipStream_t stream) {
  const int*     prg  = (const int*)d_in[0];
  const uint8_t* pm   = (const uint8_t*)d_in[1];
  const float*   emb  = (const float*)d_in[2];
  const float*   pos  = (const float*)d_in[3];
  const float*   Uw   = (const float*)d_in[4];
  const float*   Vw   = (const float*)d_in[5];
  const float*   Ww   = (const float*)d_in[6];
  const float*   keys = (const float*)d_in[7];
  float* W   = (float*)d_ws;
  float* out = (float*)d_out;

  hipLaunchKernelGGL(k_detect, dim3(128),    dim3(256), 0, stream, pm, (int*)d_ws + FLAG_OFF);
  hipLaunchKernelGGL(k_enc,    dim3(B_*T_),  dim3(128), 0, stream, prg, pm, emb, pos, Ww, keys, W);
  hipLaunchKernelGGL(k_kv,     dim3(B_*K_),  dim3(128), 0, stream, keys, Vw, W);
  hipLaunchKernelGGL(k_scan,   dim3(B_*4),   dim3(64),  0, stream, W, Uw, out);
}

// Round 7
// 487.230 us; speedup vs baseline: 1.1387x; 1.0583x over previous
//
#include <hip/hip_runtime.h>
#include <hip/hip_bf16.h>
#include <stdint.h>

#define B_ 64
#define T_ 128
#define L_ 32
#define D_ 128
#define K_ 64

// workspace offsets in 4-byte units
#define FLAG_OFF 0                                 // 128 per-block detect flags
#define SM_OFF   256
#define ENC_OFF  (SM_OFF + B_*T_)                 // [B][T][D] f32
#define SW_OFF   (ENC_OFF + B_*T_*D_)             // [B][T][D] f32  (s @ Ww)
#define KS_OFF   (SW_OFF + B_*T_*D_)              // [B][T][K] f32  (keys . s)
#define KV_OFF   (KS_OFF + B_*T_*K_)              // [B][K][D] f32  (keys @ Vw)

typedef __attribute__((ext_vector_type(8))) short short8b;   // 8 bf16 = 4 VGPR
typedef __attribute__((ext_vector_type(4))) float f32x4;

union frag_cast { uint4 u; short8b s; };

__device__ __forceinline__ float sigmoidf_(float x){ return 1.0f/(1.0f + __expf(-x)); }

__device__ __forceinline__ unsigned short bfb(float x){
  __hip_bfloat16 h = __float2bfloat16(x);                    // RNE
  return __builtin_bit_cast(unsigned short, h);
}
__device__ __forceinline__ float bf2f(unsigned short u){
  return __uint_as_float(((unsigned)u) << 16);
}

// --- K0: parallel detect of prgrph_mask dtype (1-byte bool vs 4-byte int32).
__global__ __launch_bounds__(256) void k_detect(const uint8_t* __restrict__ m,
                                                int* __restrict__ flags){
  const unsigned* w = (const unsigned*)m;
  const int base = blockIdx.x * 512;
  unsigned acc = 0;
  acc |= w[base + threadIdx.x]       & 0xFFFFFF00u;
  acc |= w[base + threadIdx.x + 256] & 0xFFFFFF00u;
  int any = __syncthreads_or((int)(acc != 0u));
  if(threadIdx.x == 0) flags[blockIdx.x] = any;   // 1 => bool bytes, 0 => int32
}

// --- K1: per (b,t): enc row, SW = enc@Ww, KS = keys.enc, sent_mask ---
__global__ __launch_bounds__(128) void k_enc(const int* __restrict__ prg,
                                             const uint8_t* __restrict__ pm8,
                                             const float* __restrict__ emb,
                                             const float* __restrict__ pos,
                                             const float* __restrict__ Ww,
                                             const float* __restrict__ keys,
                                             float* __restrict__ W){
  const int bt = blockIdx.x;
  const int b  = bt / T_;
  const int d  = threadIdx.x;
  int myf  = ((const int*)W)[FLAG_OFF + (d & 127)];
  int flag = __syncthreads_or(myf);
  __shared__ float keysl[K_*129];
  __shared__ float encl[D_];
  for(int r=0;r<K_;r++) keysl[r*129 + d] = keys[(b*K_ + r)*D_ + d];
  const int* pmi = (const int*)pm8;
  float acc = 0.f; int anym = 0;
  for(int l=0;l<L_;l++){
    int off = bt*L_ + l;
    int m = flag ? (int)pm8[off] : pmi[off];
    if(m){
      anym = 1;
      int idx = prg[off];
      acc += emb[idx*D_ + d] * pos[l*D_ + d];
    }
  }
  encl[d] = acc;
  W[ENC_OFF + bt*D_ + d] = acc;
  __syncthreads();
  float sw = 0.f;
  for(int e=0;e<D_;e++) sw += encl[e] * Ww[e*D_ + d];
  W[SW_OFF + bt*D_ + d] = sw;
  if(d < K_){
    float ks = 0.f;
    for(int dd=0;dd<D_;dd++) ks += keysl[d*129 + dd] * encl[dd];
    W[KS_OFF + bt*K_ + d] = ks;
  }
  if(d==0) W[SM_OFF + bt] = anym ? 1.f : 0.f;
}

// --- K2: KV = keys @ Vw ---
__global__ __launch_bounds__(128) void k_kv(const float* __restrict__ keys,
                                            const float* __restrict__ Vw,
                                            float* __restrict__ W){
  const int bk = blockIdx.x;
  const int d  = threadIdx.x;
  __shared__ float kr[D_];
  kr[d] = keys[bk*D_ + d];
  __syncthreads();
  float acc = 0.f;
  for(int e=0;e<D_;e++) acc += kr[e] * Vw[e*D_ + d];
  W[KV_OFF + bk*D_ + d] = acc;
}

// --- K3: MFMA scan; zero-repack permuted-k MFMA + 8-deep LDS ring so the
// steady-state loop touches NO global memory (per-step 1KB staged 7-9 steps
// ahead by the same wave; commit happens >=1 full step after issue -> no
// vmcnt stalls; ring reads are LDS broadcast, conflict-free, prefetch-depth
// covered). Single-wave block: DS pipe is in-order, no barriers anywhere.
// C-layout: e = lane&15, d = 16rt+4q+r. State vY = unnormalized v (h = n*v).
__global__ __launch_bounds__(64,1) void k_scan(const float* __restrict__ W,
                                               const float* __restrict__ Uw,
                                               float* __restrict__ out){
  const int b    = blockIdx.x >> 2;
  const int kg   = blockIdx.x & 3;
  const int lane = threadIdx.x;
  const int e    = lane & 15;
  const int q    = lane >> 4;

  __shared__ float ring [8*256];   // [slot][0..127]=ENC row, [128..255]=SW row
  __shared__ float ringk[8*20];    // [slot][0..15]=ks(entity), [16]=sm

  // ---- one-time: U^T A-frags with permuted k-mapping
  // ufrag[rt][kc][j] = bf16( Uw[32kc + 16*(j>>2) + 4q + (j&3)][16rt + e] )
  short8b ufrag[8][4];
  #pragma unroll
  for(int rt=0; rt<8; ++rt){
    #pragma unroll
    for(int kc=0; kc<4; ++kc){
      const float* r0 = &Uw[(32*kc + 4*q)*D_ + 16*rt + e];
      short8b f;
      #pragma unroll
      for(int j=0;j<8;++j) f[j] = (short)bfb(r0[((j>>2)*16 + (j&3))*D_]);
      ufrag[rt][kc] = f;
    }
  }
  f32x4 kvv[8];
  {
    const float* kvp = &W[KV_OFF + (b*K_ + kg*16 + e)*D_ + 4*q];
    #pragma unroll
    for(int rt=0;rt<8;++rt) kvv[rt] = *(const f32x4*)&kvp[16*rt];
  }
  f32x4 vY[8];
  #pragma unroll
  for(int rt=0;rt<8;++rt) vY[rt] = 0.f;

  const float* ENC = &W[ENC_OFF + b*T_*D_];
  const float* SWg = &W[SW_OFF  + b*T_*D_];
  const float* KSg = &W[KS_OFF  + b*T_*K_];
  const float* SM  = &W[SM_OFF  + b*T_];

  // issue global loads for step t (clamped); lane<32 loads ENC quad, else SW quad
  auto issue = [&](int t, f32x4& g, float& k, float& m){
    int tL = (t < T_) ? t : (T_-1);
    const float* src = (lane < 32) ? &ENC[tL*D_ + lane*4]
                                   : &SWg[tL*D_ + (lane-32)*4];
    g = *(const f32x4*)src;
    k = KSg[tL*K_ + kg*16 + e];
    m = SM[tL];
  };
  // commit staged regs into ring slot t&7
  auto commit = [&](int t, const f32x4& g, float k, float m){
    int slot = t & 7;
    *(f32x4*)&ring[slot*256 + lane*4] = g;
    if(lane < 16)   ringk[slot*20 + lane] = k;
    if(lane == 16)  ringk[slot*20 + 16]   = m;
  };

  auto dostep = [&](int t, float sm){
    if(sm != 0.f){
      int slot = t & 7;
      // ds_reads issued first; latency hidden under pack + reduction work
      f32x4 sv[8], sw[8];
      #pragma unroll
      for(int rt=0;rt<8;++rt){
        sv[rt] = *(const f32x4*)&ring[slot*256 +       16*rt + 4*q];
        sw[rt] = *(const f32x4*)&ring[slot*256 + 128 + 16*rt + 4*q];
      }
      float ks = ringk[slot*20 + e];

      // in-lane B-frag pack (hi + lo residual)
      short8b bhi[4], blo[4];
      #pragma unroll
      for(int kc=0;kc<4;++kc){
        const f32x4& va = vY[2*kc];
        const f32x4& vb = vY[2*kc+1];
        unsigned short a0=bfb(va[0]), a1=bfb(va[1]), a2=bfb(va[2]), a3=bfb(va[3]);
        unsigned short b0=bfb(vb[0]), b1=bfb(vb[1]), b2=bfb(vb[2]), b3=bfb(vb[3]);
        frag_cast fh;
        fh.u = make_uint4(((unsigned)a1<<16)|a0, ((unsigned)a3<<16)|a2,
                          ((unsigned)b1<<16)|b0, ((unsigned)b3<<16)|b2);
        unsigned short c0=bfb(va[0]-bf2f(a0)), c1=bfb(va[1]-bf2f(a1));
        unsigned short c2=bfb(va[2]-bf2f(a2)), c3=bfb(va[3]-bf2f(a3));
        unsigned short d0=bfb(vb[0]-bf2f(b0)), d1=bfb(vb[1]-bf2f(b1));
        unsigned short d2=bfb(vb[2]-bf2f(b2)), d3=bfb(vb[3]-bf2f(b3));
        frag_cast fl;
        fl.u = make_uint4(((unsigned)c1<<16)|c0, ((unsigned)c3<<16)|c2,
                          ((unsigned)d1<<16)|d0, ((unsigned)d3<<16)|d2);
        bhi[kc] = fh.s;
        blo[kc] = fl.s;
      }

      // norm + gate partials, 4-way to cut serial FMA latency
      float n0=0.f,n1=0.f,n2=0.f,n3=0.f, g0=0.f,g1=0.f,g2=0.f,g3=0.f;
      #pragma unroll
      for(int rt=0;rt<8;++rt){
        n0 += vY[rt][0]*vY[rt][0];  g0 += vY[rt][0]*sv[rt][0];
        n1 += vY[rt][1]*vY[rt][1];  g1 += vY[rt][1]*sv[rt][1];
        n2 += vY[rt][2]*vY[rt][2];  g2 += vY[rt][2]*sv[rt][2];
        n3 += vY[rt][3]*vY[rt][3];  g3 += vY[rt][3]*sv[rt][3];
      }
      float ns = (n0+n1)+(n2+n3);
      float gs = (g0+g1)+(g2+g3);
      ns += __shfl_xor(ns,16);
      ns += __shfl_xor(ns,32);
      gs += __shfl_xor(gs,16);
      gs += __shfl_xor(gs,32);
      float n = rsqrtf(fmaxf(ns, 1e-12f));
      float g = sigmoidf_(fmaf(n, gs, ks));

      // acc = U^T v  (scaled by n in epilogue)
      f32x4 acc[8];
      #pragma unroll
      for(int rt=0;rt<8;++rt) acc[rt] = 0.f;
      #pragma unroll
      for(int rt=0;rt<8;++rt){
        #pragma unroll
        for(int kc=0;kc<4;++kc){
          acc[rt] = __builtin_amdgcn_mfma_f32_16x16x32_bf16(ufrag[rt][kc], bhi[kc], acc[rt], 0,0,0);
          acc[rt] = __builtin_amdgcn_mfma_f32_16x16x32_bf16(ufrag[rt][kc], blo[kc], acc[rt], 0,0,0);
        }
      }

      // epilogue: x = n*acc + sw + kv; ht = sigmoid(x); v' = n*v + g*ht
      #pragma unroll
      for(int rt=0;rt<8;++rt){
        #pragma unroll
        for(int r=0;r<4;++r){
          float x  = fmaf(n, acc[rt][r], sw[rt][r] + kvv[rt][r]);
          float ht = sigmoidf_(x);
          vY[rt][r] = fmaf(g, ht, n*vY[rt][r]);
        }
      }
    }
  };

  // ---- prologue: serial-fill slots 0..6; stage 7 -> A, 8 -> B
  f32x4 gT; float kT, mT;
  #pragma unroll 1
  for(int s=0; s<7; ++s){ issue(s, gT, kT, mT); commit(s, gT, kT, mT); }
  f32x4 gA, gB; float kA,kB,mA,mB;
  issue(7, gA, kA, mA);
  issue(8, gB, kB, mB);
  float smC = ringk[0*20 + 16];   // sm for step 0 (carried)

  // ---- main loop, unroll-2 (half k: commit k+7, issue k+9, process k)
  #pragma unroll 1
  for(int t=0; t<T_; t+=2){
    commit(t+7, gA, kA, mA);            // staged 2 half-steps ago -> no vmcnt stall
    issue (t+9, gA, kA, mA);
    float smN = ringk[((t+1)&7)*20 + 16];
    dostep(t, smC);
    commit(t+8, gB, kB, mB);
    issue (t+10, gB, kB, mB);
    float smN2 = ringk[((t+2)&7)*20 + 16];
    dostep(t+1, smN);
    smC = smN2;
  }

  // final normalize h = n*v and write out[b, kg*16+e, 16rt+4q+r]
  float ns = 0.f;
  #pragma unroll
  for(int rt=0;rt<8;++rt){
    #pragma unroll
    for(int r=0;r<4;++r) ns += vY[rt][r]*vY[rt][r];
  }
  ns += __shfl_xor(ns,16);
  ns += __shfl_xor(ns,32);
  float n = rsqrtf(fmaxf(ns, 1e-12f));
  float* op = &out[(b*K_ + kg*16 + e)*D_ + 4*q];
  #pragma unroll
  for(int rt=0;rt<8;++rt){
    f32x4 o;
    #pragma unroll
    for(int r=0;r<4;++r) o[r] = vY[rt][r]*n;
    *(f32x4*)&op[16*rt] = o;
  }
}

extern "C" void kernel_launch(void* const* d_in, const int* in_sizes, int n_in,
                              void* d_out, int out_size, void* d_ws, size_t ws_size,
                              hipStream_t stream) {
  const int*     prg  = (const int*)d_in[0];
  const uint8_t* pm   = (const uint8_t*)d_in[1];
  const float*   emb  = (const float*)d_in[2];
  const float*   pos  = (const float*)d_in[3];
  const float*   Uw   = (const float*)d_in[4];
  const float*   Vw   = (const float*)d_in[5];
  const float*   Ww   = (const float*)d_in[6];
  const float*   keys = (const float*)d_in[7];
  float* W   = (float*)d_ws;
  float* out = (float*)d_out;

  hipLaunchKernelGGL(k_detect, dim3(128),    dim3(256), 0, stream, pm, (int*)d_ws + FLAG_OFF);
  hipLaunchKernelGGL(k_enc,    dim3(B_*T_),  dim3(128), 0, stream, prg, pm, emb, pos, Ww, keys, W);
  hipLaunchKernelGGL(k_kv,     dim3(B_*K_),  dim3(128), 0, stream, keys, Vw, W);
  hipLaunchKernelGGL(k_scan,   dim3(B_*4),   dim3(64),  0, stream, W, Uw, out);
}